// Round 1
// baseline (239.122 us; speedup 1.0000x reference)
//
#include <hip/hip_runtime.h>
#include <hip/hip_bf16.h>
#include <math.h>

#define EMBED 768
#define NHEAD 12
#define HDIM 64
#define SEQ 2048
#define BATCH 4

typedef __hip_bfloat16 bf16;
typedef __attribute__((ext_vector_type(8))) short bf16x8;   // 8 bf16 / 4 VGPRs
typedef __attribute__((ext_vector_type(4))) short s16x4;
typedef __attribute__((ext_vector_type(4))) float f32x4;
typedef __attribute__((ext_vector_type(2))) unsigned int u32x2;

__device__ inline float b2f(bf16 v) { return __bfloat162float(v); }
__device__ inline bf16 f2b(float v) { return __float2bfloat16(v); }
__device__ inline unsigned pk2(float a, float b) {
  return (unsigned)__bfloat16_as_ushort(f2b(a)) |
         ((unsigned)__bfloat16_as_ushort(f2b(b)) << 16);
}

// async global->LDS, 16B per lane. LDS dest = wave-uniform base + lane*16.
__device__ inline void gl_lds16(const bf16* g, bf16* l) {
  __builtin_amdgcn_global_load_lds(
      (const __attribute__((address_space(1))) void*)g,
      (__attribute__((address_space(3))) void*)l, 16, 0, 0);
}

#define NX4  (BATCH * SEQ * EMBED / 4)
#define NWQ4 (3 * EMBED * EMBED / 4)
#define NWP4 (EMBED * EMBED / 4)

// ---------------------------------------------------------------------------
// One fused f32->bf16 convert for x, w_qkv, w_proj (segmented index space).
// ---------------------------------------------------------------------------
__global__ __launch_bounds__(256) void cvt_all(
    const float* __restrict__ x, const float* __restrict__ wq,
    const float* __restrict__ wp, bf16* __restrict__ xb,
    bf16* __restrict__ wqb, bf16* __restrict__ wpb) {
  int i = blockIdx.x * 256 + threadIdx.x;
  const float* src;
  bf16* dst;
  int k;
  if (i < NX4) {
    src = x; dst = xb; k = i;
  } else if (i < NX4 + NWQ4) {
    src = wq; dst = wqb; k = i - NX4;
  } else if (i < NX4 + NWQ4 + NWP4) {
    src = wp; dst = wpb; k = i - NX4 - NWQ4;
  } else {
    return;
  }
  float4 v = ((const float4*)src)[k];
  s16x4 o;
  o[0] = (short)__bfloat16_as_ushort(f2b(v.x));
  o[1] = (short)__bfloat16_as_ushort(f2b(v.y));
  o[2] = (short)__bfloat16_as_ushort(f2b(v.z));
  o[3] = (short)__bfloat16_as_ushort(f2b(v.w));
  *(s16x4*)(dst + 4 * (size_t)k) = o;
}

// ---------------------------------------------------------------------------
// MFMA GEMM, operand-swapped (computes C^T tiles) — verified R11/R12, frozen.
// MODE 0: scatter Q(x 0.125*log2e) -> [B,H,N,D], K -> [B,H,N,D],
//         V -> [B,H,D,N] (bf16)
// MODE 1: outF[m,o] f32 row-major
// ---------------------------------------------------------------------------
template <int MODE>
__global__ __launch_bounds__(256) void gemm_mfma(
    const bf16* __restrict__ A, const bf16* __restrict__ W,
    const float* __restrict__ bias, float* __restrict__ outF,
    bf16* __restrict__ outQ, bf16* __restrict__ outK, bf16* __restrict__ outV,
    int M, int N, int K) {
  __shared__ bf16 As[128][32];
  __shared__ bf16 Bs[128][32];
  const int t = threadIdx.x;
  const int w = t >> 6;
  const int lane = t & 63;
  const int g = lane >> 4, c = lane & 15;
  const int m0 = blockIdx.y * 128, n0 = blockIdx.x * 128;
  const int wr = (w >> 1) * 64;   // m-dim tile base (As)
  const int wc = (w & 1) * 64;    // o-dim tile base (Bs)

  const int srow = lane >> 2;
  const int sseg = (lane & 3) * 8;

  f32x4 acc[4][4] = {};   // acc[i][j]: i over o-tiles (W), j over m-tiles (x)

  for (int k0 = 0; k0 < K; k0 += 32) {
#pragma unroll
    for (int i = 0; i < 2; i++) {
      int r = w * 32 + i * 16;
      gl_lds16(A + (size_t)(m0 + r + srow) * K + k0 + sseg, &As[r][0]);
      gl_lds16(W + (size_t)(n0 + r + srow) * K + k0 + sseg, &Bs[r][0]);
    }
    __syncthreads();

    bf16x8 xf[4], wf[4];
#pragma unroll
    for (int j = 0; j < 4; j++)
      xf[j] = *(const bf16x8*)&As[wr + j * 16 + c][g * 8];
#pragma unroll
    for (int i = 0; i < 4; i++)
      wf[i] = *(const bf16x8*)&Bs[wc + i * 16 + c][g * 8];
#pragma unroll
    for (int i = 0; i < 4; i++)
#pragma unroll
      for (int j = 0; j < 4; j++)
        acc[i][j] = __builtin_amdgcn_mfma_f32_16x16x32_bf16(wf[i], xf[j],
                                                            acc[i][j], 0, 0, 0);
    __syncthreads();
  }

  // epilogue: D^T tile — row = o (4 consecutive per thread), col = m (lane c)
#pragma unroll
  for (int i = 0; i < 4; i++) {
    const int ob = n0 + wc + i * 16 + g * 4;     // o base, +r consecutive
    const f32x4 bv = *(const f32x4*)&bias[ob];   // 16B-aligned
    int which = 0, hh = 0, d0 = 0;
    if (MODE == 0) {
      which = ob / EMBED;
      int rem = ob - which * EMBED;
      hh = rem >> 6;
      d0 = rem & 63;
    }
#pragma unroll
    for (int j = 0; j < 4; j++) {
      const int m = m0 + wr + j * 16 + c;
      f32x4 v = acc[i][j] + bv;
      if (MODE == 0) {
        const int bb = m >> 11, n = m & 2047;
        const size_t bh = (size_t)bb * NHEAD + hh;
        if (which == 0) {
          s16x4 q4;
#pragma unroll
          for (int r = 0; r < 4; r++)
            q4[r] = (short)__bfloat16_as_ushort(f2b(v[r] * 0.1803368801f));
          *(s16x4*)&outQ[(bh * SEQ + n) * HDIM + d0] = q4;
        } else if (which == 1) {
          s16x4 k4;
#pragma unroll
          for (int r = 0; r < 4; r++)
            k4[r] = (short)__bfloat16_as_ushort(f2b(v[r]));
          *(s16x4*)&outK[(bh * SEQ + n) * HDIM + d0] = k4;
        } else {
#pragma unroll
          for (int r = 0; r < 4; r++)
            outV[(bh * HDIM + d0 + r) * SEQ + n] = f2b(v[r]);
        }
      } else {
        *(f32x4*)&outF[(size_t)m * N + ob] = v;
      }
    }
  }
}

// ---------------------------------------------------------------------------
// Flash MFMA attention v8 — sync-overhead halved vs v7:
//  * Ks/Vts double-buffered -> ONE __syncthreads per K/V tile (was 2).
//    Both K(jt+1) and V(jt+1) DMAs issue at the TOP of iteration jt into
//    buf p^1; the single end barrier provides WAR protection for buf reuse
//    AND the vmcnt drain, with a full iteration (~6k cyc >> ~900 cyc HBM
//    latency) of overlap instead of one phase.
//  * Waves no longer phase-lockstep S vs softmax/PV -> MFMA/VALU phases of
//    different waves overlap on each SIMD (R13 theory: sync-bound, MfmaUtil
//    28% + VALUBusy 36% + 18% HBM).
//  * s_setprio(1) around both MFMA clusters (T5: +4-7% attn, m191).
//  * Pt is per-wave private — needs no barrier (same-wave lgkm ordering).
// LDS 51.2 KB -> still 3 blocks/CU (grid 768 caps at 3/CU anyway).
//   S^T = K . Q^T ; O^T = V^T . P^T  (fragment maps verified R3-R12, frozen)
// ---------------------------------------------------------------------------
__global__ __launch_bounds__(256, 4) void attn_mfma(
    const bf16* __restrict__ Q, const bf16* __restrict__ Kk,
    const bf16* __restrict__ V, bf16* __restrict__ O) {
  __shared__ bf16 Ks[2][64 * 64];
  __shared__ bf16 Vts[2][64 * 64];
  __shared__ bf16 Pt[8][16 * 72];

  const int blk = blockIdx.x;
  const int bh = blk >> 4;               // 16 q-tiles (of 128) per (b,h)
  const int qt = blk & 15;
  const int bb = bh / NHEAD;
  const int h = bh % NHEAD;
  const int t = threadIdx.x;
  const int lane = t & 63;
  const int w = t >> 6;
  const int g = lane >> 4;
  const int c = lane & 15;
  const size_t base = (size_t)bh * SEQ * HDIM;
  const int mb0 = qt * 128 + w * 16;     // q-group 0 rows
  const int mb1 = mb0 + 64;              // q-group 1 rows

  // DMA lane mapping (XOR chunk swizzle for K/V, verified R5-R12)
  const int r8 = lane >> 3;
  const int l8 = lane & 7;
  const int gch = l8 ^ (r8 & 7);
  const int q0 = w * 2, q1 = w * 2 + 1;

  // Q fragments (B operand), one pair per q-group
  bf16x8 qa[2][2];
#pragma unroll
  for (int kh = 0; kh < 2; kh++) {
    qa[0][kh] = *(const bf16x8*)(Q + base + (size_t)(mb0 + c) * HDIM + kh * 32 + g * 8);
    qa[1][kh] = *(const bf16x8*)(Q + base + (size_t)(mb1 + c) * HDIM + kh * 32 + g * 8);
  }

  // all-ones A fragment for the l-row-sum MFMA
  bf16x8 ones;
#pragma unroll
  for (int i = 0; i < 8; i++) ones[i] = (short)0x3F80;

  f32x4 o[2][4] = {};
  f32x4 o_l[2] = {};

  // prologue: DMA tile 0 (K and V) into buf 0, drain before first use
  gl_lds16(Kk + base + (size_t)(q0 * 8 + r8) * HDIM + gch * 8, &Ks[0][q0 * 8 * 64]);
  gl_lds16(Kk + base + (size_t)(q1 * 8 + r8) * HDIM + gch * 8, &Ks[0][q1 * 8 * 64]);
  gl_lds16(V + base + (size_t)(q0 * 8 + r8) * SEQ + gch * 8, &Vts[0][q0 * 8 * 64]);
  gl_lds16(V + base + (size_t)(q1 * 8 + r8) * SEQ + gch * 8, &Vts[0][q1 * 8 * 64]);
  __syncthreads();

  bf16* const Pt0 = Pt[w * 2];
  bf16* const Pt1 = Pt[w * 2 + 1];

  for (int jt = 0; jt < SEQ / 64; jt++) {
    const int p = jt & 1;

    // issue next tile's DMA first — lands any time before the end barrier
    if (jt + 1 < SEQ / 64) {
      const int jb = (jt + 1) * 64;
      gl_lds16(Kk + base + (size_t)(jb + q0 * 8 + r8) * HDIM + gch * 8,
               &Ks[p ^ 1][q0 * 8 * 64]);
      gl_lds16(Kk + base + (size_t)(jb + q1 * 8 + r8) * HDIM + gch * 8,
               &Ks[p ^ 1][q1 * 8 * 64]);
      gl_lds16(V + base + (size_t)(q0 * 8 + r8) * SEQ + jb + gch * 8,
               &Vts[p ^ 1][q0 * 8 * 64]);
      gl_lds16(V + base + (size_t)(q1 * 8 + r8) * SEQ + jb + gch * 8,
               &Vts[p ^ 1][q1 * 8 * 64]);
    }

    // S^T = K . Q^T — each kb read feeds both q-groups
    f32x4 s[2][4] = {};
    __builtin_amdgcn_s_setprio(1);
#pragma unroll
    for (int nt = 0; nt < 4; nt++) {
#pragma unroll
      for (int kh = 0; kh < 2; kh++) {
        bf16x8 kb = *(const bf16x8*)&Ks[p][(nt * 16 + c) * 64 + ((kh * 4 + g) ^ (c & 7)) * 8];
        s[0][nt] = __builtin_amdgcn_mfma_f32_16x16x32_bf16(kb, qa[0][kh], s[0][nt], 0, 0, 0);
        s[1][nt] = __builtin_amdgcn_mfma_f32_16x16x32_bf16(kb, qa[1][kh], s[1][nt], 0, 0, 0);
      }
    }
    __builtin_amdgcn_s_setprio(0);

    // p = exp2(s); pack 4 consecutive j; plain stride-72 Pt, per group
#pragma unroll
    for (int nt = 0; nt < 4; nt++) {
      float a0 = __builtin_amdgcn_exp2f(s[0][nt][0]);
      float a1 = __builtin_amdgcn_exp2f(s[0][nt][1]);
      float a2 = __builtin_amdgcn_exp2f(s[0][nt][2]);
      float a3 = __builtin_amdgcn_exp2f(s[0][nt][3]);
      u32x2 pw0 = {pk2(a0, a1), pk2(a2, a3)};
      *(u32x2*)&Pt0[c * 72 + nt * 16 + g * 4] = pw0;
      float b0 = __builtin_amdgcn_exp2f(s[1][nt][0]);
      float b1 = __builtin_amdgcn_exp2f(s[1][nt][1]);
      float b2 = __builtin_amdgcn_exp2f(s[1][nt][2]);
      float b3 = __builtin_amdgcn_exp2f(s[1][nt][3]);
      u32x2 pw1 = {pk2(b0, b1), pk2(b2, b3)};
      *(u32x2*)&Pt1[c * 72 + nt * 16 + g * 4] = pw1;
    }
    bf16x8 pb[2][2];
    pb[0][0] = *(const bf16x8*)&Pt0[c * 72 + g * 8];
    pb[0][1] = *(const bf16x8*)&Pt0[c * 72 + 32 + g * 8];
    pb[1][0] = *(const bf16x8*)&Pt1[c * 72 + g * 8];
    pb[1][1] = *(const bf16x8*)&Pt1[c * 72 + 32 + g * 8];

    // O^T += V^T . P^T — each vb read feeds both q-groups;
    // l += ones . P^T in the MFMA pipe
    __builtin_amdgcn_s_setprio(1);
#pragma unroll
    for (int dt = 0; dt < 4; dt++) {
      bf16x8 vb0 = *(const bf16x8*)&Vts[p][(dt * 16 + c) * 64 + ((0 + g) ^ (c & 7)) * 8];
      bf16x8 vb1 = *(const bf16x8*)&Vts[p][(dt * 16 + c) * 64 + ((4 + g) ^ (c & 7)) * 8];
      o[0][dt] = __builtin_amdgcn_mfma_f32_16x16x32_bf16(vb0, pb[0][0], o[0][dt], 0, 0, 0);
      o[0][dt] = __builtin_amdgcn_mfma_f32_16x16x32_bf16(vb1, pb[0][1], o[0][dt], 0, 0, 0);
      o[1][dt] = __builtin_amdgcn_mfma_f32_16x16x32_bf16(vb0, pb[1][0], o[1][dt], 0, 0, 0);
      o[1][dt] = __builtin_amdgcn_mfma_f32_16x16x32_bf16(vb1, pb[1][1], o[1][dt], 0, 0, 0);
    }
    o_l[0] = __builtin_amdgcn_mfma_f32_16x16x32_bf16(ones, pb[0][0], o_l[0], 0, 0, 0);
    o_l[0] = __builtin_amdgcn_mfma_f32_16x16x32_bf16(ones, pb[0][1], o_l[0], 0, 0, 0);
    o_l[1] = __builtin_amdgcn_mfma_f32_16x16x32_bf16(ones, pb[1][0], o_l[1], 0, 0, 0);
    o_l[1] = __builtin_amdgcn_mfma_f32_16x16x32_bf16(ones, pb[1][1], o_l[1], 0, 0, 0);
    __builtin_amdgcn_s_setprio(0);

    // single barrier: WAR protection for buf p^1 + drains this iter's DMA
    if (jt + 1 < SEQ / 64) __syncthreads();
  }

  // epilogue: l[c] replicated in every o_l reg — no shuffles; packed stores
#pragma unroll
  for (int grp = 0; grp < 2; grp++) {
    const float inv = __builtin_amdgcn_rcpf(o_l[grp][0]);
    const int mb = grp ? mb1 : mb0;
    const size_t rowoff = ((size_t)bb * SEQ + mb + c) * EMBED + h * 64 + g * 4;
#pragma unroll
    for (int dt = 0; dt < 4; dt++) {
      s16x4 ov;
#pragma unroll
      for (int r = 0; r < 4; r++)
        ov[r] = (short)__bfloat16_as_ushort(f2b(o[grp][dt][r] * inv));
      *(s16x4*)&O[rowoff + dt * 16] = ov;
    }
  }
}

// ---------------------------------------------------------------------------
extern "C" void kernel_launch(void* const* d_in, const int* in_sizes, int n_in,
                              void* d_out, int out_size, void* d_ws,
                              size_t ws_size, hipStream_t stream) {
  const float* x      = (const float*)d_in[0];
  const float* w_qkv  = (const float*)d_in[1];
  const float* b_qkv  = (const float*)d_in[2];
  const float* w_proj = (const float*)d_in[3];
  const float* b_proj = (const float*)d_in[4];

  const size_t per = (size_t)BATCH * NHEAD * SEQ * HDIM;
  bf16* Qp = (bf16*)d_ws;
  bf16* Kp = Qp + per;
  bf16* Vp = Kp + per;                 // [B,H,D,N]
  bf16* xb = Vp + per;                 // x bf16; reused as AO after QKV GEMM
  bf16* wqkvb = xb + per;
  bf16* wprojb = wqkvb + (size_t)3 * EMBED * EMBED;
  bf16* AO = xb;

  const int ncvt = NX4 + NWQ4 + NWP4;  // f32x4 groups total
  cvt_all<<<dim3((ncvt + 255) / 256), 256, 0, stream>>>(x, w_qkv, w_proj, xb,
                                                        wqkvb, wprojb);

  dim3 g1(2304 / 128, 8192 / 128);
  gemm_mfma<0><<<g1, 256, 0, stream>>>(xb, wqkvb, b_qkv, nullptr, Qp, Kp, Vp,
                                       BATCH * SEQ, 3 * EMBED, EMBED);

  // 128 q-rows per block: B*H*(SEQ/128) = 768 blocks, 51.2 KB LDS
  attn_mfma<<<dim3(BATCH * NHEAD * (SEQ / 128)), 256, 0, stream>>>(Qp, Kp, Vp, AO);

  dim3 g2(768 / 128, 8192 / 128);
  gemm_mfma<1><<<g2, 256, 0, stream>>>(AO, wprojb, b_proj, (float*)d_out,
                                       nullptr, nullptr, nullptr, BATCH * SEQ,
                                       EMBED, EMBED);
}

// Round 2
// 222.838 us; speedup vs baseline: 1.0731x; 1.0731x over previous
//
#include <hip/hip_runtime.h>
#include <hip/hip_bf16.h>
#include <math.h>

#define EMBED 768
#define NHEAD 12
#define HDIM 64
#define SEQ 2048
#define BATCH 4

typedef __hip_bfloat16 bf16;
typedef __attribute__((ext_vector_type(8))) short bf16x8;   // 8 bf16 / 4 VGPRs
typedef __attribute__((ext_vector_type(4))) short s16x4;
typedef __attribute__((ext_vector_type(4))) float f32x4;
typedef __attribute__((ext_vector_type(2))) unsigned int u32x2;

__device__ inline float b2f(bf16 v) { return __bfloat162float(v); }
__device__ inline bf16 f2b(float v) { return __float2bfloat16(v); }
__device__ inline unsigned pk2(float a, float b) {
  return (unsigned)__bfloat16_as_ushort(f2b(a)) |
         ((unsigned)__bfloat16_as_ushort(f2b(b)) << 16);
}

// async global->LDS, 16B per lane. LDS dest = wave-uniform base + lane*16.
__device__ inline void gl_lds16(const bf16* g, bf16* l) {
  __builtin_amdgcn_global_load_lds(
      (const __attribute__((address_space(1))) void*)g,
      (__attribute__((address_space(3))) void*)l, 16, 0, 0);
}

#define NX4  (BATCH * SEQ * EMBED / 4)
#define NWQ4 (3 * EMBED * EMBED / 4)
#define NWP4 (EMBED * EMBED / 4)

// ---------------------------------------------------------------------------
// One fused f32->bf16 convert for x, w_qkv, w_proj (segmented index space).
// ---------------------------------------------------------------------------
__global__ __launch_bounds__(256) void cvt_all(
    const float* __restrict__ x, const float* __restrict__ wq,
    const float* __restrict__ wp, bf16* __restrict__ xb,
    bf16* __restrict__ wqb, bf16* __restrict__ wpb) {
  int i = blockIdx.x * 256 + threadIdx.x;
  const float* src;
  bf16* dst;
  int k;
  if (i < NX4) {
    src = x; dst = xb; k = i;
  } else if (i < NX4 + NWQ4) {
    src = wq; dst = wqb; k = i - NX4;
  } else if (i < NX4 + NWQ4 + NWP4) {
    src = wp; dst = wpb; k = i - NX4 - NWQ4;
  } else {
    return;
  }
  float4 v = ((const float4*)src)[k];
  s16x4 o;
  o[0] = (short)__bfloat16_as_ushort(f2b(v.x));
  o[1] = (short)__bfloat16_as_ushort(f2b(v.y));
  o[2] = (short)__bfloat16_as_ushort(f2b(v.z));
  o[3] = (short)__bfloat16_as_ushort(f2b(v.w));
  *(s16x4*)(dst + 4 * (size_t)k) = o;
}

// ---------------------------------------------------------------------------
// MFMA GEMM, operand-swapped (computes C^T tiles).
// R14: BK=64 (half the barrier-drain events of BK=32; K=768 -> 12 steps).
//   * single-buffered As/Bs [128][64] = 32 KB LDS (occupancy still VGPR-capped
//     at 3 waves/SIMD — avoids m132's BK=128 LDS cliff).
//   * k-halves looped (h=0,1) so fragment VGPRs are NOT doubled.
//   * 128B rows would be a 16-way bank conflict on b128 fragment reads; fixed
//     with the both-sides XOR swizzle (rule 21): DMA source chunk
//     (lane&7)^(lane>>3), read slot (h*4+g)^(c&7). slot^row cancels, so the
//     register fragment contents are identical to the BK=32 layout.
// MODE 0: scatter Q(x 0.125*log2e) -> [B,H,N,D], K -> [B,H,N,D],
//         V -> [B,H,D,N] (bf16)
// MODE 1: outF[m,o] f32 row-major
// ---------------------------------------------------------------------------
template <int MODE>
__global__ __launch_bounds__(256) void gemm_mfma(
    const bf16* __restrict__ A, const bf16* __restrict__ W,
    const float* __restrict__ bias, float* __restrict__ outF,
    bf16* __restrict__ outQ, bf16* __restrict__ outK, bf16* __restrict__ outV,
    int M, int N, int K) {
  __shared__ bf16 As[128][64];
  __shared__ bf16 Bs[128][64];
  const int t = threadIdx.x;
  const int w = t >> 6;
  const int lane = t & 63;
  const int g = lane >> 4, c = lane & 15;
  const int m0 = blockIdx.y * 128, n0 = blockIdx.x * 128;
  const int wr = (w >> 1) * 64;   // m-dim tile base (As)
  const int wc = (w & 1) * 64;    // o-dim tile base (Bs)

  // DMA mapping: 1KB per instr = 8 rows x 128B. Source chunk pre-swizzled.
  const int srow = lane >> 3;          // 0..7 row within 8-row stripe
  const int l8 = lane & 7;             // LDS 16B-slot within row
  const int sseg = (l8 ^ srow) * 8;    // swizzled global chunk (bf16 elems)

  f32x4 acc[4][4] = {};   // acc[i][j]: i over o-tiles (W), j over m-tiles (x)

  for (int k0 = 0; k0 < K; k0 += 64) {
#pragma unroll
    for (int i = 0; i < 4; i++) {
      int r = w * 32 + i * 8;
      gl_lds16(A + (size_t)(m0 + r + srow) * K + k0 + sseg, &As[r][0]);
      gl_lds16(W + (size_t)(n0 + r + srow) * K + k0 + sseg, &Bs[r][0]);
    }
    __syncthreads();

#pragma unroll
    for (int h = 0; h < 2; h++) {
      bf16x8 xf[4], wf[4];
#pragma unroll
      for (int j = 0; j < 4; j++)
        xf[j] = *(const bf16x8*)&As[wr + j * 16 + c][((h * 4 + g) ^ (c & 7)) * 8];
#pragma unroll
      for (int i = 0; i < 4; i++)
        wf[i] = *(const bf16x8*)&Bs[wc + i * 16 + c][((h * 4 + g) ^ (c & 7)) * 8];
#pragma unroll
      for (int i = 0; i < 4; i++)
#pragma unroll
        for (int j = 0; j < 4; j++)
          acc[i][j] = __builtin_amdgcn_mfma_f32_16x16x32_bf16(wf[i], xf[j],
                                                              acc[i][j], 0, 0, 0);
    }
    __syncthreads();
  }

  // epilogue: D^T tile — row = o (4 consecutive per thread), col = m (lane c)
#pragma unroll
  for (int i = 0; i < 4; i++) {
    const int ob = n0 + wc + i * 16 + g * 4;     // o base, +r consecutive
    const f32x4 bv = *(const f32x4*)&bias[ob];   // 16B-aligned
    int which = 0, hh = 0, d0 = 0;
    if (MODE == 0) {
      which = ob / EMBED;
      int rem = ob - which * EMBED;
      hh = rem >> 6;
      d0 = rem & 63;
    }
#pragma unroll
    for (int j = 0; j < 4; j++) {
      const int m = m0 + wr + j * 16 + c;
      f32x4 v = acc[i][j] + bv;
      if (MODE == 0) {
        const int bb = m >> 11, n = m & 2047;
        const size_t bh = (size_t)bb * NHEAD + hh;
        if (which == 0) {
          s16x4 q4;
#pragma unroll
          for (int r = 0; r < 4; r++)
            q4[r] = (short)__bfloat16_as_ushort(f2b(v[r] * 0.1803368801f));
          *(s16x4*)&outQ[(bh * SEQ + n) * HDIM + d0] = q4;
        } else if (which == 1) {
          s16x4 k4;
#pragma unroll
          for (int r = 0; r < 4; r++)
            k4[r] = (short)__bfloat16_as_ushort(f2b(v[r]));
          *(s16x4*)&outK[(bh * SEQ + n) * HDIM + d0] = k4;
        } else {
#pragma unroll
          for (int r = 0; r < 4; r++)
            outV[(bh * HDIM + d0 + r) * SEQ + n] = f2b(v[r]);
        }
      } else {
        *(f32x4*)&outF[(size_t)m * N + ob] = v;
      }
    }
  }
}

// ---------------------------------------------------------------------------
// Flash MFMA attention v7 — REVERTED to the measured-best structure (82.3 µs).
// R14 post-mortem: v8 (dbuf + single barrier + setprio) was NULL-to-negative
// (84.7 µs, VALUBusy 36->53%) — attn is not barrier/drain-bound; plateau is
// structural (LDS traffic + 3 waves/SIMD latency hiding). v7 frozen.
//   S^T = K . Q^T ; O^T = V^T . P^T  (fragment maps verified R3-R12)
// Block = 128 q-rows, 4 waves x 2 groups of 16. LDS 34.8 KB; grid 768 = 3/CU.
// Per iter: S(ks) -> B1 -> DMA K(jt+1) -> softmax/Pt/PV(vs) -> B2 -> DMA V(jt+1).
// ---------------------------------------------------------------------------
__global__ __launch_bounds__(256, 4) void attn_mfma(
    const bf16* __restrict__ Q, const bf16* __restrict__ Kk,
    const bf16* __restrict__ V, bf16* __restrict__ O) {
  __shared__ bf16 Ks[64 * 64];
  __shared__ bf16 Vts[64 * 64];
  __shared__ bf16 Pt[8][16 * 72];

  const int blk = blockIdx.x;
  const int bh = blk >> 4;               // 16 q-tiles (of 128) per (b,h)
  const int qt = blk & 15;
  const int bb = bh / NHEAD;
  const int h = bh % NHEAD;
  const int t = threadIdx.x;
  const int lane = t & 63;
  const int w = t >> 6;
  const int g = lane >> 4;
  const int c = lane & 15;
  const size_t base = (size_t)bh * SEQ * HDIM;
  const int mb0 = qt * 128 + w * 16;     // q-group 0 rows
  const int mb1 = mb0 + 64;              // q-group 1 rows

  // DMA lane mapping (XOR chunk swizzle for K/V, verified R5-R12)
  const int r8 = lane >> 3;
  const int l8 = lane & 7;
  const int gch = l8 ^ (r8 & 7);
  const int q0 = w * 2, q1 = w * 2 + 1;

  // Q fragments (B operand), one pair per q-group
  bf16x8 qa[2][2];
#pragma unroll
  for (int kh = 0; kh < 2; kh++) {
    qa[0][kh] = *(const bf16x8*)(Q + base + (size_t)(mb0 + c) * HDIM + kh * 32 + g * 8);
    qa[1][kh] = *(const bf16x8*)(Q + base + (size_t)(mb1 + c) * HDIM + kh * 32 + g * 8);
  }

  // all-ones A fragment for the l-row-sum MFMA
  bf16x8 ones;
#pragma unroll
  for (int i = 0; i < 8; i++) ones[i] = (short)0x3F80;

  f32x4 o[2][4] = {};
  f32x4 o_l[2] = {};

  // prologue: DMA tile 0 (K and V), drain before first use
  gl_lds16(Kk + base + (size_t)(q0 * 8 + r8) * HDIM + gch * 8, &Ks[q0 * 8 * 64]);
  gl_lds16(Kk + base + (size_t)(q1 * 8 + r8) * HDIM + gch * 8, &Ks[q1 * 8 * 64]);
  gl_lds16(V + base + (size_t)(q0 * 8 + r8) * SEQ + gch * 8, &Vts[q0 * 8 * 64]);
  gl_lds16(V + base + (size_t)(q1 * 8 + r8) * SEQ + gch * 8, &Vts[q1 * 8 * 64]);
  __syncthreads();

  bf16* const Pt0 = Pt[w * 2];
  bf16* const Pt1 = Pt[w * 2 + 1];

  for (int jt = 0; jt < SEQ / 64; jt++) {
    // S^T = K . Q^T — each kb read feeds both q-groups
    f32x4 s[2][4] = {};
#pragma unroll
    for (int nt = 0; nt < 4; nt++) {
#pragma unroll
      for (int kh = 0; kh < 2; kh++) {
        bf16x8 kb = *(const bf16x8*)&Ks[(nt * 16 + c) * 64 + ((kh * 4 + g) ^ (c & 7)) * 8];
        s[0][nt] = __builtin_amdgcn_mfma_f32_16x16x32_bf16(kb, qa[0][kh], s[0][nt], 0, 0, 0);
        s[1][nt] = __builtin_amdgcn_mfma_f32_16x16x32_bf16(kb, qa[1][kh], s[1][nt], 0, 0, 0);
      }
    }

    __syncthreads();  // B1: all waves done reading Ks; drains V(jt) DMA
    if (jt + 1 < SEQ / 64) {  // DMA K(jt+1); softmax+PV time to land
      const int jb = (jt + 1) * 64;
      gl_lds16(Kk + base + (size_t)(jb + q0 * 8 + r8) * HDIM + gch * 8, &Ks[q0 * 8 * 64]);
      gl_lds16(Kk + base + (size_t)(jb + q1 * 8 + r8) * HDIM + gch * 8, &Ks[q1 * 8 * 64]);
    }

    // p = exp2(s); pack 4 consecutive j; plain stride-72 Pt, per group
#pragma unroll
    for (int nt = 0; nt < 4; nt++) {
      float a0 = __builtin_amdgcn_exp2f(s[0][nt][0]);
      float a1 = __builtin_amdgcn_exp2f(s[0][nt][1]);
      float a2 = __builtin_amdgcn_exp2f(s[0][nt][2]);
      float a3 = __builtin_amdgcn_exp2f(s[0][nt][3]);
      u32x2 pw0 = {pk2(a0, a1), pk2(a2, a3)};
      *(u32x2*)&Pt0[c * 72 + nt * 16 + g * 4] = pw0;
      float b0 = __builtin_amdgcn_exp2f(s[1][nt][0]);
      float b1 = __builtin_amdgcn_exp2f(s[1][nt][1]);
      float b2 = __builtin_amdgcn_exp2f(s[1][nt][2]);
      float b3 = __builtin_amdgcn_exp2f(s[1][nt][3]);
      u32x2 pw1 = {pk2(b0, b1), pk2(b2, b3)};
      *(u32x2*)&Pt1[c * 72 + nt * 16 + g * 4] = pw1;
    }
    bf16x8 pb[2][2];
    pb[0][0] = *(const bf16x8*)&Pt0[c * 72 + g * 8];
    pb[0][1] = *(const bf16x8*)&Pt0[c * 72 + 32 + g * 8];
    pb[1][0] = *(const bf16x8*)&Pt1[c * 72 + g * 8];
    pb[1][1] = *(const bf16x8*)&Pt1[c * 72 + 32 + g * 8];

    // O^T += V^T . P^T — each vb read feeds both q-groups;
    // l += ones . P^T in the MFMA pipe
#pragma unroll
    for (int dt = 0; dt < 4; dt++) {
      bf16x8 vb0 = *(const bf16x8*)&Vts[(dt * 16 + c) * 64 + ((0 + g) ^ (c & 7)) * 8];
      bf16x8 vb1 = *(const bf16x8*)&Vts[(dt * 16 + c) * 64 + ((4 + g) ^ (c & 7)) * 8];
      o[0][dt] = __builtin_amdgcn_mfma_f32_16x16x32_bf16(vb0, pb[0][0], o[0][dt], 0, 0, 0);
      o[0][dt] = __builtin_amdgcn_mfma_f32_16x16x32_bf16(vb1, pb[0][1], o[0][dt], 0, 0, 0);
      o[1][dt] = __builtin_amdgcn_mfma_f32_16x16x32_bf16(vb0, pb[1][0], o[1][dt], 0, 0, 0);
      o[1][dt] = __builtin_amdgcn_mfma_f32_16x16x32_bf16(vb1, pb[1][1], o[1][dt], 0, 0, 0);
    }
    o_l[0] = __builtin_amdgcn_mfma_f32_16x16x32_bf16(ones, pb[0][0], o_l[0], 0, 0, 0);
    o_l[0] = __builtin_amdgcn_mfma_f32_16x16x32_bf16(ones, pb[0][1], o_l[0], 0, 0, 0);
    o_l[1] = __builtin_amdgcn_mfma_f32_16x16x32_bf16(ones, pb[1][0], o_l[1], 0, 0, 0);
    o_l[1] = __builtin_amdgcn_mfma_f32_16x16x32_bf16(ones, pb[1][1], o_l[1], 0, 0, 0);

    __syncthreads();  // B2: all waves done reading Vts; drains K(jt+1) DMA
    if (jt + 1 < SEQ / 64) {  // DMA V(jt+1); S-phase time to land
      const int jb = (jt + 1) * 64;
      gl_lds16(V + base + (size_t)(q0 * 8 + r8) * SEQ + jb + gch * 8, &Vts[q0 * 8 * 64]);
      gl_lds16(V + base + (size_t)(q1 * 8 + r8) * SEQ + jb + gch * 8, &Vts[q1 * 8 * 64]);
    }
  }

  // epilogue: l[c] replicated in every o_l reg — no shuffles; packed stores
#pragma unroll
  for (int grp = 0; grp < 2; grp++) {
    const float inv = __builtin_amdgcn_rcpf(o_l[grp][0]);
    const int mb = grp ? mb1 : mb0;
    const size_t rowoff = ((size_t)bb * SEQ + mb + c) * EMBED + h * 64 + g * 4;
#pragma unroll
    for (int dt = 0; dt < 4; dt++) {
      s16x4 ov;
#pragma unroll
      for (int r = 0; r < 4; r++)
        ov[r] = (short)__bfloat16_as_ushort(f2b(o[grp][dt][r] * inv));
      *(s16x4*)&O[rowoff + dt * 16] = ov;
    }
  }
}

// ---------------------------------------------------------------------------
extern "C" void kernel_launch(void* const* d_in, const int* in_sizes, int n_in,
                              void* d_out, int out_size, void* d_ws,
                              size_t ws_size, hipStream_t stream) {
  const float* x      = (const float*)d_in[0];
  const float* w_qkv  = (const float*)d_in[1];
  const float* b_qkv  = (const float*)d_in[2];
  const float* w_proj = (const float*)d_in[3];
  const float* b_proj = (const float*)d_in[4];

  const size_t per = (size_t)BATCH * NHEAD * SEQ * HDIM;
  bf16* Qp = (bf16*)d_ws;
  bf16* Kp = Qp + per;
  bf16* Vp = Kp + per;                 // [B,H,D,N]
  bf16* xb = Vp + per;                 // x bf16; reused as AO after QKV GEMM
  bf16* wqkvb = xb + per;
  bf16* wprojb = wqkvb + (size_t)3 * EMBED * EMBED;
  bf16* AO = xb;

  const int ncvt = NX4 + NWQ4 + NWP4;  // f32x4 groups total
  cvt_all<<<dim3((ncvt + 255) / 256), 256, 0, stream>>>(x, w_qkv, w_proj, xb,
                                                        wqkvb, wprojb);

  dim3 g1(2304 / 128, 8192 / 128);
  gemm_mfma<0><<<g1, 256, 0, stream>>>(xb, wqkvb, b_qkv, nullptr, Qp, Kp, Vp,
                                       BATCH * SEQ, 3 * EMBED, EMBED);

  // 128 q-rows per block: B*H*(SEQ/128) = 768 blocks, 34.8 KB LDS
  attn_mfma<<<dim3(BATCH * NHEAD * (SEQ / 128)), 256, 0, stream>>>(Qp, Kp, Vp, AO);

  dim3 g2(768 / 128, 8192 / 128);
  gemm_mfma<1><<<g2, 256, 0, stream>>>(AO, wprojb, b_proj, (float*)d_out,
                                       nullptr, nullptr, nullptr, BATCH * SEQ,
                                       EMBED, EMBED);
}